// Round 1
// baseline (304.456 us; speedup 1.0000x reference)
//
#include <hip/hip_runtime.h>
#include <hip/hip_cooperative_groups.h>

namespace cg = cooperative_groups;

// Single cooperative dispatch: per-block partials -> grid.sync() -> block 0
// finalizes. Removes the second dispatch (~3-4 us of the ~12 us we control;
// the other ~83 us is two 256 MiB harness poison fills at ~81% HBM peak,
// which are outside kernel_launch's control).
//
// ws layout: ws[0 .. GRID-1] = per-block float partials.

#define BLOCK 256
#define GRID  1024                    // 4 blocks/CU on 256 CUs -> co-resident
#define POS_PER_THREAD 8
#define POS_PER_BLOCK (BLOCK * POS_PER_THREAD)   // 2048 positions per chunk

typedef float f32x4 __attribute__((ext_vector_type(4)));

__global__ __launch_bounds__(BLOCK, 4) void ce_fused(
    const float* __restrict__ y_true,
    const float* __restrict__ y_pred,
    const int*   __restrict__ doc_len,
    float*       __restrict__ partials,
    float*       __restrict__ out,
    int L, int chunks_per_row, int total_chunks, int B)
{
    float acc0 = 0.0f, acc1 = 0.0f;   // two accumulators for FMA-chain ILP

    // grid-stride over chunks: block gets chunks c and c+GRID (rows b, b+256)
    for (int c = blockIdx.x; c < total_chunks; c += GRID) {
        const int b     = c / chunks_per_row;
        const int chunk = c - b * chunks_per_row;
        const int dl    = doc_len[b];             // wave-uniform scalar load
        const int start = chunk * POS_PER_BLOCK;
        if (start >= dl) continue;

        const size_t row2 = (size_t)b * (size_t)L * 2;

        if (start + POS_PER_BLOCK <= dl) {
            // fully-valid chunk (common case): no per-position guards,
            // nontemporal loads (read-once stream, keep L2 clean)
            #pragma unroll
            for (int j = 0; j < POS_PER_THREAD / 2; ++j) {
                const int pos = start + j * (BLOCK * 2) + (int)threadIdx.x * 2;
                const size_t e = row2 + (size_t)pos * 2;     // 16B aligned
                const f32x4 t = __builtin_nontemporal_load((const f32x4*)(y_true + e));
                const f32x4 p = __builtin_nontemporal_load((const f32x4*)(y_pred + e));
                // one-hot: exactly one of (t.x,t.y) is 1 -> branchless FMA
                acc0 += t.x * (-__logf(p.x)) + t.y * (-__logf(p.y));
                acc1 += t.z * (-__logf(p.z)) + t.w * (-__logf(p.w));
            }
        } else {
            // partial chunk (at most one per row): guarded path
            #pragma unroll
            for (int j = 0; j < POS_PER_THREAD / 2; ++j) {
                const int pos = start + j * (BLOCK * 2) + (int)threadIdx.x * 2;
                if (pos < dl) {
                    const size_t e = row2 + (size_t)pos * 2;
                    const f32x4 t = *(const f32x4*)(y_true + e);
                    const f32x4 p = *(const f32x4*)(y_pred + e);
                    acc0 += t.x * (-__logf(p.x)) + t.y * (-__logf(p.y));
                    if (pos + 1 < dl)
                        acc1 += t.z * (-__logf(p.z)) + t.w * (-__logf(p.w));
                }
            }
        }
    }

    // wave-64 butterfly reduce
    float local = acc0 + acc1;
    #pragma unroll
    for (int off = 32; off > 0; off >>= 1)
        local += __shfl_down(local, off, 64);

    __shared__ float wsum[BLOCK / 64];
    const int lane = threadIdx.x & 63;
    const int wid  = threadIdx.x >> 6;
    if (lane == 0) wsum[wid] = local;
    __syncthreads();
    if (threadIdx.x == 0) {
        float s = 0.0f;
        #pragma unroll
        for (int w = 0; w < BLOCK / 64; ++w) s += wsum[w];
        partials[blockIdx.x] = s;
    }

    __threadfence();          // device-scope visibility of partials (cross-XCD)
    cg::this_grid().sync();

    // ---- finalize: block 0 only ----
    if (blockIdx.x == 0) {
        float s = 0.0f;
        #pragma unroll 4
        for (int i = threadIdx.x; i < GRID; i += BLOCK)   // 4 iters
            s += partials[i];

        int len = 0;
        for (int i = threadIdx.x; i < B; i += BLOCK)       // 2 iters at B=512
            len += doc_len[i];

        #pragma unroll
        for (int off = 32; off > 0; off >>= 1) {
            s   += __shfl_down(s, off, 64);
            len += __shfl_down(len, off, 64);
        }

        __shared__ float fsum[BLOCK / 64];
        __shared__ int   isum[BLOCK / 64];
        if (lane == 0) { fsum[wid] = s; isum[wid] = len; }
        __syncthreads();
        if (threadIdx.x == 0) {
            float fs = 0.0f; int is = 0;
            #pragma unroll
            for (int w = 0; w < BLOCK / 64; ++w) { fs += fsum[w]; is += isum[w]; }
            out[0] = fs / (float)is;
        }
    }
}

extern "C" void kernel_launch(void* const* d_in, const int* in_sizes, int n_in,
                              void* d_out, int out_size, void* d_ws, size_t ws_size,
                              hipStream_t stream)
{
    const float* y_true  = (const float*)d_in[0];
    const float* y_pred  = (const float*)d_in[1];
    const int*   doc_len = (const int*)d_in[2];
    float*       out     = (float*)d_out;
    float*       ws      = (float*)d_ws;

    int B = in_sizes[2];
    int L = in_sizes[0] / (2 * B);
    int chunks_per_row = (L + POS_PER_BLOCK - 1) / POS_PER_BLOCK;
    int total_chunks   = B * chunks_per_row;

    void* args[] = { &y_true, &y_pred, &doc_len, &ws, &out,
                     &L, &chunks_per_row, &total_chunks, &B };
    hipLaunchCooperativeKernel((const void*)ce_fused, dim3(GRID), dim3(BLOCK),
                               args, 0, stream);
}

// Round 2
// 95.452 us; speedup vs baseline: 3.1896x; 3.1896x over previous
//
#include <hip/hip_runtime.h>

// Two-dispatch, zero-atomic structure (same-address atomics ~10ns each
// serialized; a 1-block finalize dispatch is cheaper). R1 post-mortem:
// cooperative grid.sync() costs ~200us on this harness -- never fuse via
// grid sync here. ws layout: ws[0 .. npart-1] = per-block float partials.

#define BLOCK 256
#define POS_PER_THREAD 8
#define POS_PER_BLOCK (BLOCK * POS_PER_THREAD)   // 2048 positions per block

typedef float f32x4 __attribute__((ext_vector_type(4)));

__global__ __launch_bounds__(BLOCK) void ce_main(
    const float* __restrict__ y_true,
    const float* __restrict__ y_pred,
    const int*   __restrict__ doc_len,
    float*       __restrict__ partials,
    int L, int chunks_per_row)
{
    const int b     = blockIdx.x / chunks_per_row;
    const int chunk = blockIdx.x % chunks_per_row;
    const int dl    = doc_len[b];                 // wave-uniform scalar load

    const int start = chunk * POS_PER_BLOCK;
    if (start >= dl) {
        if (threadIdx.x == 0) partials[blockIdx.x] = 0.0f;
        return;
    }

    const size_t row_base = (size_t)b * L;
    float acc0 = 0.0f, acc1 = 0.0f;

    if (start + POS_PER_BLOCK <= dl) {
        // fully-valid chunk (avg ~2 of 4 per row): no per-position guards;
        // all 8 loads issue back-to-back for memory-level parallelism
        #pragma unroll
        for (int j = 0; j < POS_PER_THREAD / 2; ++j) {
            const int pos = start + j * (BLOCK * 2) + (int)threadIdx.x * 2;
            const size_t e = (row_base + (size_t)pos) * 2;   // 16B aligned
            const f32x4 t = *(const f32x4*)(y_true + e);
            const f32x4 p = *(const f32x4*)(y_pred + e);
            // one-hot: exactly one of (t.x,t.y) is 1 -> branchless FMA
            acc0 += t.x * (-__logf(p.x)) + t.y * (-__logf(p.y));
            acc1 += t.z * (-__logf(p.z)) + t.w * (-__logf(p.w));
        }
    } else {
        // boundary chunk (at most one per row): guarded path
        #pragma unroll
        for (int j = 0; j < POS_PER_THREAD / 2; ++j) {
            const int pos = start + j * (BLOCK * 2) + (int)threadIdx.x * 2;
            if (pos < dl) {
                const size_t e = (row_base + (size_t)pos) * 2;
                const f32x4 t = *(const f32x4*)(y_true + e);
                const f32x4 p = *(const f32x4*)(y_pred + e);
                acc0 += t.x * (-__logf(p.x)) + t.y * (-__logf(p.y));
                if (pos + 1 < dl)
                    acc1 += t.z * (-__logf(p.z)) + t.w * (-__logf(p.w));
            }
        }
    }

    // wave-64 butterfly reduce
    float local = acc0 + acc1;
    #pragma unroll
    for (int off = 32; off > 0; off >>= 1)
        local += __shfl_down(local, off, 64);

    __shared__ float wsum[BLOCK / 64];
    const int lane = threadIdx.x & 63;
    const int wid  = threadIdx.x >> 6;
    if (lane == 0) wsum[wid] = local;
    __syncthreads();
    if (threadIdx.x == 0) {
        float s = 0.0f;
        #pragma unroll
        for (int w = 0; w < BLOCK / 64; ++w) s += wsum[w];
        partials[blockIdx.x] = s;
    }
}

__global__ __launch_bounds__(BLOCK) void ce_finalize(
    const float* __restrict__ partials, int npart,
    const int*   __restrict__ doc_len,  int B,
    float*       __restrict__ out)
{
    float s = 0.0f;
    // vectorized when npart % 4 == 0 (it is: 2048), fallback loop otherwise
    if ((npart & 3) == 0) {
        const f32x4* p4 = (const f32x4*)partials;
        const int n4 = npart >> 2;
        for (int i = threadIdx.x; i < n4; i += BLOCK) {
            const f32x4 v = p4[i];
            s += (v.x + v.y) + (v.z + v.w);
        }
    } else {
        for (int i = threadIdx.x; i < npart; i += BLOCK)
            s += partials[i];
    }

    int len = 0;
    for (int i = threadIdx.x; i < B; i += BLOCK)
        len += doc_len[i];

    #pragma unroll
    for (int off = 32; off > 0; off >>= 1) {
        s   += __shfl_down(s, off, 64);
        len += __shfl_down(len, off, 64);
    }

    __shared__ float fsum[BLOCK / 64];
    __shared__ int   isum[BLOCK / 64];
    const int lane = threadIdx.x & 63;
    const int wid  = threadIdx.x >> 6;
    if (lane == 0) { fsum[wid] = s; isum[wid] = len; }
    __syncthreads();
    if (threadIdx.x == 0) {
        float fs = 0.0f; int is = 0;
        #pragma unroll
        for (int w = 0; w < BLOCK / 64; ++w) { fs += fsum[w]; is += isum[w]; }
        out[0] = fs / (float)is;
    }
}

extern "C" void kernel_launch(void* const* d_in, const int* in_sizes, int n_in,
                              void* d_out, int out_size, void* d_ws, size_t ws_size,
                              hipStream_t stream)
{
    const float* y_true  = (const float*)d_in[0];
    const float* y_pred  = (const float*)d_in[1];
    const int*   doc_len = (const int*)d_in[2];
    float*       out     = (float*)d_out;
    float*       ws      = (float*)d_ws;

    const int B = in_sizes[2];
    const int L = in_sizes[0] / (2 * B);
    const int chunks_per_row = (L + POS_PER_BLOCK - 1) / POS_PER_BLOCK;
    const int npart = B * chunks_per_row;

    ce_main<<<dim3(npart), BLOCK, 0, stream>>>(y_true, y_pred, doc_len, ws, L, chunks_per_row);
    ce_finalize<<<dim3(1), BLOCK, 0, stream>>>(ws, npart, doc_len, B, out);
}